// Round 1
// baseline (1400.475 us; speedup 1.0000x reference)
//
#include <hip/hip_runtime.h>
#include <hip/hip_bf16.h>
#include <math.h>

// ---------------------------------------------------------------------------
// Kernel 1: fp32 GEMM  C[4096,600] = x[4096,1024] @ W[1024,600] + b[600]
// Tiled: BM=128, BN=64, BK=16; 256 threads; 8x4 micro-tile per thread.
// ---------------------------------------------------------------------------
#define BM 128
#define BN 64
#define BK 16

__global__ __launch_bounds__(256) void gemm_bias_kernel(
    const float* __restrict__ A,    // x [4096,1024]
    const float* __restrict__ W,    // [1024,600]
    const float* __restrict__ bias, // [600]
    float* __restrict__ C)          // [4096,600]
{
    const int M = 4096, K = 1024, N = 600;
    (void)M;
    __shared__ float As[BK][BM + 4];   // [16][132] — stride 132 f (16B-aligned rows)
    __shared__ float Bs[BK][BN + 4];   // [16][68]  — stride 68 f  (16B-aligned rows)

    const int t  = threadIdx.x;
    const int tx = t & 15;        // 16 col-groups (4 cols each)
    const int ty = t >> 4;        // 16 row-groups (8 rows each)
    const int m0 = blockIdx.x * BM;
    const int n0 = blockIdx.y * BN;

    float acc[8][4];
    #pragma unroll
    for (int i = 0; i < 8; ++i)
        #pragma unroll
        for (int j = 0; j < 4; ++j) acc[i][j] = 0.f;

    for (int k0 = 0; k0 < K; k0 += BK) {
        // --- stage A: 128x16 = 512 float4, 2 per thread, transposed into LDS
        #pragma unroll
        for (int i = 0; i < 2; ++i) {
            int f4 = t + i * 256;          // 0..511
            int m  = f4 >> 2;              // 0..127
            int k4 = f4 & 3;               // 0..3
            const float4 v = *(const float4*)&A[(size_t)(m0 + m) * K + k0 + k4 * 4];
            As[k4 * 4 + 0][m] = v.x;
            As[k4 * 4 + 1][m] = v.y;
            As[k4 * 4 + 2][m] = v.z;
            As[k4 * 4 + 3][m] = v.w;
        }
        // --- stage B: 16x64 = 256 float4, 1 per thread (guard last col-tile)
        {
            int n4 = t & 15, k = t >> 4;
            int n  = n0 + n4 * 4;
            float4 v = make_float4(0.f, 0.f, 0.f, 0.f);
            if (n + 4 <= N) v = *(const float4*)&W[(size_t)(k0 + k) * N + n];
            *(float4*)&Bs[k][n4 * 4] = v;
        }
        __syncthreads();

        #pragma unroll
        for (int k = 0; k < BK; ++k) {
            float4 a0 = *(const float4*)&As[k][ty * 8];
            float4 a1 = *(const float4*)&As[k][ty * 8 + 4];
            float4 b0 = *(const float4*)&Bs[k][tx * 4];
            float a[8] = {a0.x, a0.y, a0.z, a0.w, a1.x, a1.y, a1.z, a1.w};
            float bb[4] = {b0.x, b0.y, b0.z, b0.w};
            #pragma unroll
            for (int i = 0; i < 8; ++i)
                #pragma unroll
                for (int j = 0; j < 4; ++j)
                    acc[i][j] = fmaf(a[i], bb[j], acc[i][j]);
        }
        __syncthreads();
    }

    // epilogue: + bias, guarded store (N=600 not multiple of 64)
    #pragma unroll
    for (int i = 0; i < 8; ++i) {
        int row = m0 + ty * 8 + i;
        #pragma unroll
        for (int j = 0; j < 4; ++j) {
            int col = n0 + tx * 4 + j;
            if (col < N) C[(size_t)row * N + col] = acc[i][j] + bias[col];
        }
    }
}

// ---------------------------------------------------------------------------
// Kernel 2: per-row fused scores -> softmax -> fill(1e-6) -> scatter-add.
// One block (256 threads = 4 waves) per batch row.
// ---------------------------------------------------------------------------
__global__ __launch_bounds__(256) void fused_score_softmax_scatter(
    const float* __restrict__ ep,   // emb_pred [B,600]
    const float* __restrict__ emb,  // [B,50,600]
    const int*   __restrict__ ids,  // [B,50]
    float* __restrict__ out)        // [B,40000]
{
    const int EC = 600, NC = 50, V = 40000;
    const int b    = blockIdx.x;
    const int t    = threadIdx.x;
    const int lane = t & 63;
    const int wave = t >> 6;

    __shared__ float s_ep[600];
    __shared__ float s_p[64];
    __shared__ int   s_id[64];

    // stage emb_pred row (600 f32 = 150 float4) in LDS
    const float4* ep4   = (const float4*)(ep + (size_t)b * EC);
    float4*       s_ep4 = (float4*)s_ep;
    for (int i = t; i < 150; i += 256) s_ep4[i] = ep4[i];
    if (t < NC) s_id[t] = ids[b * NC + t];
    __syncthreads();

    // 50 dot products, wave-parallel (each wave takes n = wave, wave+4, ...)
    const float* embrow = emb + (size_t)b * NC * EC;
    for (int n = wave; n < NC; n += 4) {
        const float4* e4 = (const float4*)(embrow + n * EC);
        float partial = 0.f;
        for (int jf = lane; jf < 150; jf += 64) {
            float4 e = e4[jf];
            float4 q = s_ep4[jf];
            partial += e.x * q.x + e.y * q.y + e.z * q.z + e.w * q.w;
        }
        #pragma unroll
        for (int off = 32; off > 0; off >>= 1) partial += __shfl_down(partial, off);
        if (lane == 0) s_p[n] = partial;
    }
    __syncthreads();

    // softmax over 50 scores (wave 0)
    if (wave == 0) {
        float v = (lane < NC) ? s_p[lane] : -INFINITY;
        float m = v;
        #pragma unroll
        for (int off = 32; off > 0; off >>= 1) m = fmaxf(m, __shfl_xor(m, off));
        float e = (lane < NC) ? expf(v - m) : 0.f;
        float s = e;
        #pragma unroll
        for (int off = 32; off > 0; off >>= 1) s += __shfl_xor(s, off);
        if (lane < NC) s_p[lane] = e / s;
    }
    __syncthreads();

    // fill this row of out with 1e-6 (40000 f32 = 10000 float4, coalesced)
    float4* row4 = (float4*)(out + (size_t)b * V);
    const float4 fillv = make_float4(1e-6f, 1e-6f, 1e-6f, 1e-6f);
    for (int i = t; i < V / 4; i += 256) row4[i] = fillv;
    __syncthreads();   // drains the stores before the atomics touch the row

    // scatter-add the 50 probabilities (atomics: duplicate ids must ADD)
    if (t < NC) atomicAdd(out + (size_t)b * V + s_id[t], s_p[t]);
}

// ---------------------------------------------------------------------------
extern "C" void kernel_launch(void* const* d_in, const int* in_sizes, int n_in,
                              void* d_out, int out_size, void* d_ws, size_t ws_size,
                              hipStream_t stream) {
    const float* x    = (const float*)d_in[0];   // [4096,1024]
    const float* emb  = (const float*)d_in[1];   // [4096,50,600]
    const int*   ids  = (const int*)d_in[2];     // [4096,50]
    // d_in[3] = prob (zeros) — unused; reference uses zeros_like(prob)
    const float* W    = (const float*)d_in[4];   // [1024,600]
    const float* bias = (const float*)d_in[5];   // [600]
    float* out = (float*)d_out;                  // [4096,40000]
    float* ep  = (float*)d_ws;                   // scratch: [4096,600] = 9.8 MB

    dim3 g1(4096 / BM, (600 + BN - 1) / BN);     // 32 x 10
    gemm_bias_kernel<<<g1, 256, 0, stream>>>(x, W, bias, ep);

    fused_score_softmax_scatter<<<4096, 256, 0, stream>>>(ep, emb, ids, out);
}